// Round 2
// baseline (1487.999 us; speedup 1.0000x reference)
//
#include <hip/hip_runtime.h>
#include <hip/hip_bf16.h>

#define F 128
#define F3 384
#define NRBF 20
#define NITER 3

typedef __hip_bfloat16 bf16;

__device__ __forceinline__ float b2f(bf16 v) { return __bfloat162float(v); }
__device__ __forceinline__ bf16 f2b(float v) { return __float2bfloat16(v); }

// ---------------- dtype detection: bf16 (flag=0) vs f32 (flag=1) ----------------
// Genuine bf16 data for this problem has |x| < 16 everywhere (pos in [0,2)).
// f32 bits read as u16 pairs: even halves are random mantissa bits -> many
// elements with exponent >= 140 (|x| >= 2^13) or NaN. Scan and set flag.
__global__ void detect_kernel(const unsigned short* __restrict__ raw, int n_u16,
                              int* __restrict__ flag) {
    int i = blockIdx.x * blockDim.x + threadIdx.x;
    int bad = 0;
    for (int k = i; k < n_u16; k += blockDim.x * gridDim.x) {
        unsigned e = (raw[k] >> 7) & 0xFFu;
        if (e >= 140u) bad = 1;
    }
    if (bad) atomicOr(flag, 1);
}

// ---------------- param convert (bf16 or f32 -> f32) ----------------
__global__ void cvt_dual_kernel(const void* __restrict__ src, float* __restrict__ dst,
                                int n, const int* __restrict__ flag) {
    int i = blockIdx.x * blockDim.x + threadIdx.x;
    if (i >= n) return;
    if (*flag) dst[i] = ((const float*)src)[i];
    else       dst[i] = b2f(((const bf16*)src)[i]);
}

// ---------------- geometry: dir, fcut, phi*fcut ----------------
__global__ void geom_kernel(const float* __restrict__ pos, const int* __restrict__ ii,
                            const int* __restrict__ jj, float* __restrict__ dirv,
                            float* __restrict__ fcutv, bf16* __restrict__ phifc, int E) {
    int e = blockIdx.x * blockDim.x + threadIdx.x;
    if (e >= E) return;
    int i = ii[e], j = jj[e];
    float r[3];
#pragma unroll
    for (int d = 0; d < 3; ++d) {
        float v = pos[j * 3 + d] - pos[i * 3 + d];
        if (fabsf(v) < 1e-6f) v = 1e-6f;   // reference: where(|r|<1e-6, 1e-6, r)
        r[d] = v;
    }
    float dd = sqrtf(r[0] * r[0] + r[1] * r[1] + r[2] * r[2]);
    float inv = 1.0f / dd;
    dirv[e * 3 + 0] = r[0] * inv;
    dirv[e * 3 + 1] = r[1] * inv;
    dirv[e * 3 + 2] = r[2] * inv;
    const float CUT = 5.0f;
    const float PI = 3.14159265358979323846f;
    float fc = (dd < CUT) ? 0.5f * (cosf(PI * dd / CUT) + 1.0f) : 0.0f;
    fcutv[e] = fc;
    const float width = CUT / (NRBF - 1);
    const float coeff = -0.5f / (width * width);
#pragma unroll
    for (int k = 0; k < NRBF; ++k) {
        float diff = dd - (float)k * width;
        phifc[e * NRBF + k] = f2b(expf(coeff * diff * diff) * fc);
    }
}

// ---------------- initial q from embedding ----------------
__global__ void embed_kernel(const int* __restrict__ z, const float* __restrict__ emb,
                             float* __restrict__ q, int N) {
    int idx = blockIdx.x * blockDim.x + threadIdx.x;
    if (idx >= N * F) return;
    int n = idx >> 7, f = idx & 127;
    q[idx] = emb[z[n] * F + f];
}

// ---------------- CSR build ----------------
__global__ void count_kernel(const int* __restrict__ ii, int* __restrict__ counts, int E) {
    int e = blockIdx.x * blockDim.x + threadIdx.x;
    if (e < E) atomicAdd(&counts[ii[e]], 1);
}

__global__ void scan_kernel(const int* __restrict__ counts, int* __restrict__ offs, int N) {
    __shared__ int cum[1024];
    int t = threadIdx.x;
    int chunk = (N + 1023) >> 10;
    int b = t * chunk;
    int e = b + chunk; if (e > N) e = N;
    int s = 0;
    for (int a = b; a < e; ++a) s += counts[a];
    cum[t] = s;
    __syncthreads();
    for (int o = 1; o < 1024; o <<= 1) {
        int u = (t >= o) ? cum[t - o] : 0;
        __syncthreads();
        cum[t] += u;
        __syncthreads();
    }
    int run = cum[t] - s;   // exclusive base
    for (int a = b; a < e; ++a) { offs[a] = run; run += counts[a]; }
    if (t == 1023) offs[N] = cum[1023];
}

__global__ void fill_kernel(const int* __restrict__ ii, const int* __restrict__ offs,
                            int* __restrict__ cursor, int* __restrict__ elist, int E) {
    int e = blockIdx.x * blockDim.x + threadIdx.x;
    if (e >= E) return;
    int i = ii[e];
    int p = atomicAdd(&cursor[i], 1);
    elist[offs[i] + p] = e;
}

// ---------------- per-atom x = silu(q@W1+b1)@W2+b2  (M=8 atoms/block) ----------------
__global__ void atom_x_kernel(const float* __restrict__ q_in, const float* __restrict__ W1,
                              const float* __restrict__ b1, const float* __restrict__ W2,
                              const float* __restrict__ b2, bf16* __restrict__ x, int N) {
    __shared__ float Sq[128][9];   // pad -> conflict-free writes
    __shared__ float Sh[128][9];
    int c = threadIdx.x;
    int i0 = blockIdx.x * 8;
#pragma unroll
    for (int m = 0; m < 8; ++m) {
        int i = i0 + m;
        Sq[c][m] = (i < N) ? q_in[(size_t)i * F + c] : 0.0f;
    }
    __syncthreads();
    {
        float acc[8];
        float bb = b1[c];
#pragma unroll
        for (int m = 0; m < 8; ++m) acc[m] = bb;
        for (int k = 0; k < 128; ++k) {
            float w = W1[k * F + c];
#pragma unroll
            for (int m = 0; m < 8; ++m) acc[m] += Sq[k][m] * w;
        }
#pragma unroll
        for (int m = 0; m < 8; ++m) {
            float v = acc[m];
            Sh[c][m] = v / (1.0f + expf(-v));   // silu
        }
    }
    __syncthreads();
#pragma unroll
    for (int p = 0; p < 3; ++p) {
        int c3 = p * 128 + c;
        float acc[8];
        float bb = b2[c3];
#pragma unroll
        for (int m = 0; m < 8; ++m) acc[m] = bb;
        for (int k = 0; k < 128; ++k) {
            float w = W2[k * F3 + c3];
#pragma unroll
            for (int m = 0; m < 8; ++m) acc[m] += Sh[k][m] * w;
        }
#pragma unroll
        for (int m = 0; m < 8; ++m) {
            int i = i0 + m;
            if (i < N) x[(size_t)i * F3 + c3] = f2b(acc[m]);
        }
    }
}

// ---------------- edge gather (one block per destination atom, no atomics) ----------------
__global__ void edge_gather_kernel(float* __restrict__ q, const bf16* __restrict__ mu_in,
                                   const bf16* __restrict__ x, const float* __restrict__ dirv,
                                   const float* __restrict__ fcutv, const bf16* __restrict__ phifc,
                                   const float* __restrict__ fW_f, const float* __restrict__ fb_f,
                                   int t, const int* __restrict__ offs, const int* __restrict__ elist,
                                   const int* __restrict__ jj, bf16* __restrict__ mu_out, int N) {
    int i = blockIdx.x;
    int f = threadIdx.x;
    const float* fWt = fW_f + t * F3;       // row stride 3*F*NITER = 1152
    const float* fbt = fb_f + t * F3;
    // hoist filter weight columns into registers (edge-independent)
    float w0[NRBF], w1[NRBF], w2[NRBF];
#pragma unroll
    for (int k = 0; k < NRBF; ++k) {
        const float* row = fWt + k * (3 * F * NITER);
        w0[k] = row[f];
        w1[k] = row[f + 128];
        w2[k] = row[f + 256];
    }
    float fb0 = fbt[f], fb1 = fbt[f + 128], fb2 = fbt[f + 256];
    int beg = offs[i], end = offs[i + 1];
    float accq = 0.0f, am0 = 0.0f, am1 = 0.0f, am2 = 0.0f;
    for (int l = beg; l < end; ++l) {
        int e = elist[l];
        int j = jj[e];
        float fc = fcutv[e];
        float f0 = fc * fb0, f1 = fc * fb1, f2 = fc * fb2;
#pragma unroll
        for (int k = 0; k < NRBF; ++k) {
            float ph = b2f(phifc[e * NRBF + k]);
            f0 += ph * w0[k];
            f1 += ph * w1[k];
            f2 += ph * w2[k];
        }
        const bf16* xj = x + (size_t)j * F3;
        float dq = f0 * b2f(xj[f]);
        float dR = f1 * b2f(xj[f + 128]);
        float dM = f2 * b2f(xj[f + 256]);
        accq += dq;
        float d0 = dirv[e * 3 + 0], d1 = dirv[e * 3 + 1], d2 = dirv[e * 3 + 2];
        const bf16* muj = mu_in + (size_t)j * F3;
        am0 += dR * d0 + dM * b2f(muj[f]);
        am1 += dR * d1 + dM * b2f(muj[f + 128]);
        am2 += dR * d2 + dM * b2f(muj[f + 256]);
    }
    q[(size_t)i * F + f] += accq;
    mu_out[(size_t)i * F3 + f]       = f2b(b2f(mu_in[(size_t)i * F3 + f]) + am0);
    mu_out[(size_t)i * F3 + 128 + f] = f2b(b2f(mu_in[(size_t)i * F3 + 128 + f]) + am1);
    mu_out[(size_t)i * F3 + 256 + f] = f2b(b2f(mu_in[(size_t)i * F3 + 256 + f]) + am2);
}

// ---------------- mixing (intra-atomic), M=4 atoms / 256-thread block ----------------
__global__ void mix_kernel(float* __restrict__ q, bf16* __restrict__ mu,
                           const float* __restrict__ Wmix, const float* __restrict__ W1,
                           const float* __restrict__ b1, const float* __restrict__ W2,
                           const float* __restrict__ b2, int N) {
    __shared__ float Smu[128][3][4];
    __shared__ float Sq[128][4];
    __shared__ float SV[3][128][4];
    __shared__ float SW[3][128][4];
    __shared__ float Sctx[256][4];
    __shared__ float Sh[128][4];
    __shared__ float Sx3[384][4];
    int tid = threadIdx.x;
    int i0 = blockIdx.x * 4;
#pragma unroll
    for (int m = 0; m < 4; ++m) {
        int i = i0 + m;
        if (tid < 128) Sq[tid][m] = (i < N) ? q[(size_t)i * F + tid] : 0.0f;
        for (int idx = tid; idx < F3; idx += 256) {
            int d = idx >> 7, f = idx & 127;
            Smu[f][d][m] = (i < N) ? b2f(mu[(size_t)i * F3 + idx]) : 0.0f;
        }
    }
    __syncthreads();
    // mu_mix = mu @ Wmix : cols 0..255 (V | W)
    {
        float acc[3][4];
#pragma unroll
        for (int d = 0; d < 3; ++d)
#pragma unroll
            for (int m = 0; m < 4; ++m) acc[d][m] = 0.0f;
        for (int k = 0; k < 128; ++k) {
            float w = Wmix[k * 256 + tid];
#pragma unroll
            for (int d = 0; d < 3; ++d)
#pragma unroll
                for (int m = 0; m < 4; ++m) acc[d][m] += Smu[k][d][m] * w;
        }
        int f = tid & 127;
        if (tid < 128) {
#pragma unroll
            for (int d = 0; d < 3; ++d)
#pragma unroll
                for (int m = 0; m < 4; ++m) SV[d][f][m] = acc[d][m];
        } else {
#pragma unroll
            for (int d = 0; d < 3; ++d)
#pragma unroll
                for (int m = 0; m < 4; ++m) SW[d][f][m] = acc[d][m];
        }
    }
    __syncthreads();
    if (tid < 128) {
#pragma unroll
        for (int m = 0; m < 4; ++m) {
            Sctx[tid][m] = Sq[tid][m];
            float v2 = SV[0][tid][m] * SV[0][tid][m] + SV[1][tid][m] * SV[1][tid][m] +
                       SV[2][tid][m] * SV[2][tid][m];
            Sctx[128 + tid][m] = sqrtf(v2 + 1e-8f);
        }
    }
    __syncthreads();
    if (tid < 128) {
        float acc[4];
        float bb = b1[tid];
#pragma unroll
        for (int m = 0; m < 4; ++m) acc[m] = bb;
        for (int k = 0; k < 256; ++k) {
            float w = W1[k * F + tid];
#pragma unroll
            for (int m = 0; m < 4; ++m) acc[m] += Sctx[k][m] * w;
        }
#pragma unroll
        for (int m = 0; m < 4; ++m) {
            float v = acc[m];
            Sh[tid][m] = v / (1.0f + expf(-v));
        }
    }
    __syncthreads();
    for (int c3 = tid; c3 < F3; c3 += 256) {
        float acc[4];
        float bb = b2[c3];
#pragma unroll
        for (int m = 0; m < 4; ++m) acc[m] = bb;
        for (int k = 0; k < 128; ++k) {
            float w = W2[k * F3 + c3];
#pragma unroll
            for (int m = 0; m < 4; ++m) acc[m] += Sh[k][m] * w;
        }
#pragma unroll
        for (int m = 0; m < 4; ++m) Sx3[c3][m] = acc[m];
    }
    __syncthreads();
    if (tid < 128) {
        int f = tid;
#pragma unroll
        for (int m = 0; m < 4; ++m) {
            int i = i0 + m;
            if (i >= N) continue;
            float s = SV[0][f][m] * SW[0][f][m] + SV[1][f][m] * SW[1][f][m] +
                      SV[2][f][m] * SW[2][f][m];
            q[(size_t)i * F + f] = Sq[f][m] + Sx3[f][m] + Sx3[256 + f][m] * s;
#pragma unroll
            for (int d = 0; d < 3; ++d)
                mu[(size_t)i * F3 + d * 128 + f] =
                    f2b(Smu[f][d][m] + Sx3[128 + f][m] * SW[d][f][m]);
        }
    }
}

// ---------------- output: q ‖ mu, dtype per flag ----------------
__global__ void out_kernel(const float* __restrict__ q, const bf16* __restrict__ mu,
                           void* __restrict__ out, int N, const int* __restrict__ flag) {
    int idx = blockIdx.x * blockDim.x + threadIdx.x;
    int nq = N * F;
    int tot = nq + N * F3;
    if (idx >= tot) return;
    float v = (idx < nq) ? q[idx] : b2f(mu[idx - nq]);
    if (*flag) ((float*)out)[idx] = v;
    else       ((bf16*)out)[idx] = f2b(v);
}

extern "C" void kernel_launch(void* const* d_in, const int* in_sizes, int n_in,
                              void* d_out, int out_size, void* d_ws, size_t ws_size,
                              hipStream_t stream) {
    const int* z = (const int*)d_in[0];
    const int* idx_i = (const int*)d_in[2];
    const int* idx_j = (const int*)d_in[3];

    int N = in_sizes[0];
    int E = in_sizes[2];

    char* base = (char*)d_ws;
    size_t off = 0;
    auto alloc = [&](size_t bytes) -> void* {
        void* p = base + off;
        off += (bytes + 255) & ~(size_t)255;
        return p;
    };

    int* flag = (int*)alloc(4);
    float* pos_f = (float*)alloc((size_t)in_sizes[1] * 4);
    float* emb_f = (float*)alloc((size_t)in_sizes[4] * 4);
    float* fW_f = (float*)alloc((size_t)in_sizes[5] * 4);
    float* fb_f = (float*)alloc((size_t)in_sizes[6] * 4);
    float* iW1_f = (float*)alloc((size_t)in_sizes[7] * 4);
    float* ib1_f = (float*)alloc((size_t)in_sizes[8] * 4);
    float* iW2_f = (float*)alloc((size_t)in_sizes[9] * 4);
    float* ib2_f = (float*)alloc((size_t)in_sizes[10] * 4);
    float* mWmix_f = (float*)alloc((size_t)in_sizes[11] * 4);
    float* mW1_f = (float*)alloc((size_t)in_sizes[12] * 4);
    float* mb1_f = (float*)alloc((size_t)in_sizes[13] * 4);
    float* mW2_f = (float*)alloc((size_t)in_sizes[14] * 4);
    float* mb2_f = (float*)alloc((size_t)in_sizes[15] * 4);
    float* q = (float*)alloc((size_t)N * F * 4);
    bf16* mua = (bf16*)alloc((size_t)N * F3 * 2);
    bf16* mub = (bf16*)alloc((size_t)N * F3 * 2);
    bf16* xbuf = (bf16*)alloc((size_t)N * F3 * 2);
    float* dirv = (float*)alloc((size_t)E * 3 * 4);
    float* fcutv = (float*)alloc((size_t)E * 4);
    bf16* phifc = (bf16*)alloc((size_t)E * NRBF * 2);
    int* counts = (int*)alloc((size_t)N * 4);
    int* offs = (int*)alloc((size_t)(N + 1) * 4);
    int* elist = (int*)alloc((size_t)E * 4);

    hipMemsetAsync(flag, 0, 4, stream);
    detect_kernel<<<64, 256, 0, stream>>>((const unsigned short*)d_in[1], in_sizes[1], flag);

    auto cvt = [&](int idx, float* dst) {
        int n = in_sizes[idx];
        cvt_dual_kernel<<<(n + 255) / 256, 256, 0, stream>>>(d_in[idx], dst, n, flag);
    };
    cvt(1, pos_f);
    cvt(4, emb_f);
    cvt(5, fW_f);  cvt(6, fb_f);
    cvt(7, iW1_f); cvt(8, ib1_f);
    cvt(9, iW2_f); cvt(10, ib2_f);
    cvt(11, mWmix_f);
    cvt(12, mW1_f); cvt(13, mb1_f);
    cvt(14, mW2_f); cvt(15, mb2_f);

    geom_kernel<<<(E + 255) / 256, 256, 0, stream>>>(pos_f, idx_i, idx_j, dirv, fcutv, phifc, E);
    embed_kernel<<<(N * F + 255) / 256, 256, 0, stream>>>(z, emb_f, q, N);
    hipMemsetAsync(mua, 0, (size_t)N * F3 * 2, stream);

    hipMemsetAsync(counts, 0, (size_t)N * 4, stream);
    count_kernel<<<(E + 255) / 256, 256, 0, stream>>>(idx_i, counts, E);
    scan_kernel<<<1, 1024, 0, stream>>>(counts, offs, N);
    hipMemsetAsync(counts, 0, (size_t)N * 4, stream);
    fill_kernel<<<(E + 255) / 256, 256, 0, stream>>>(idx_i, offs, counts, elist, E);

    bf16* muin = mua;
    bf16* muout = mub;
    for (int t = 0; t < NITER; ++t) {
        atom_x_kernel<<<(N + 7) / 8, 128, 0, stream>>>(q, iW1_f + t * F * F, ib1_f + t * F,
                                                       iW2_f + t * F * F3, ib2_f + t * F3, xbuf, N);
        edge_gather_kernel<<<N, 128, 0, stream>>>(q, muin, xbuf, dirv, fcutv, phifc, fW_f, fb_f,
                                                  t, offs, elist, idx_j, muout, N);
        mix_kernel<<<(N + 3) / 4, 256, 0, stream>>>(q, muout, mWmix_f + t * F * 2 * F,
                                                    mW1_f + t * 2 * F * F, mb1_f + t * F,
                                                    mW2_f + t * F * F3, mb2_f + t * F3, N);
        bf16* tm = muin; muin = muout; muout = tm;
    }

    int tot = N * (F + F3);
    out_kernel<<<(tot + 255) / 256, 256, 0, stream>>>(q, muin, d_out, N, flag);
}

// Round 3
// 890.817 us; speedup vs baseline: 1.6704x; 1.6704x over previous
//
#include <hip/hip_runtime.h>
#include <hip/hip_bf16.h>

#define F 128
#define F3 384
#define NRBF 20
#define NITER 3

typedef __hip_bfloat16 bf16;
typedef __bf16 bfrag __attribute__((ext_vector_type(8)));
typedef float f32x4 __attribute__((ext_vector_type(4)));

__device__ __forceinline__ float b2f(bf16 v) { return __bfloat162float(v); }
__device__ __forceinline__ bf16 f2b(float v) { return __float2bfloat16(v); }
__device__ __forceinline__ bfrag ldb(const bf16* p) { return *(const bfrag*)p; }
__device__ __forceinline__ bfrag ldsb(const __bf16* p) { return *(const bfrag*)p; }
__device__ __forceinline__ bfrag cvtf(const float* p) {
    bfrag r;
#pragma unroll
    for (int j = 0; j < 8; ++j) r[j] = (__bf16)p[j];
    return r;
}

// ---------------- dtype detection: bf16 (flag=0) vs f32 (flag=1) ----------------
__global__ void detect_kernel(const unsigned short* __restrict__ raw, int n_u16,
                              int* __restrict__ flag) {
    int i = blockIdx.x * blockDim.x + threadIdx.x;
    int bad = 0;
    for (int k = i; k < n_u16; k += blockDim.x * gridDim.x) {
        unsigned e = (raw[k] >> 7) & 0xFFu;
        if (e >= 140u) bad = 1;
    }
    if (bad) atomicOr(flag, 1);
}

// ---------------- param convert (bf16 or f32 -> f32) ----------------
__global__ void cvt_dual_kernel(const void* __restrict__ src, float* __restrict__ dst,
                                int n, const int* __restrict__ flag) {
    int i = blockIdx.x * blockDim.x + threadIdx.x;
    if (i >= n) return;
    if (*flag) dst[i] = ((const float*)src)[i];
    else       dst[i] = b2f(((const bf16*)src)[i]);
}

// ---------------- transpose f32 [NITER][K][Nn] -> bf16 [NITER][Nn][K] ----------------
__global__ void transpose_bf16_kernel(const float* __restrict__ src, bf16* __restrict__ dst,
                                      int K, int Nn, int total) {
    int i = blockIdx.x * blockDim.x + threadIdx.x;
    if (i >= total) return;
    int slice = K * Nn;
    int t = i / slice, j = i - t * slice;
    int n = j / K, k = j - n * K;
    dst[i] = f2b(src[t * slice + k * Nn + n]);
}

// ---------------- geometry: dir, fcut, phi*fcut ----------------
__global__ void geom_kernel(const float* __restrict__ pos, const int* __restrict__ ii,
                            const int* __restrict__ jj, float* __restrict__ dirv,
                            float* __restrict__ fcutv, bf16* __restrict__ phifc, int E) {
    int e = blockIdx.x * blockDim.x + threadIdx.x;
    if (e >= E) return;
    int i = ii[e], j = jj[e];
    float r[3];
#pragma unroll
    for (int d = 0; d < 3; ++d) {
        float v = pos[j * 3 + d] - pos[i * 3 + d];
        if (fabsf(v) < 1e-6f) v = 1e-6f;
        r[d] = v;
    }
    float dd = sqrtf(r[0] * r[0] + r[1] * r[1] + r[2] * r[2]);
    float inv = 1.0f / dd;
    dirv[e * 3 + 0] = r[0] * inv;
    dirv[e * 3 + 1] = r[1] * inv;
    dirv[e * 3 + 2] = r[2] * inv;
    const float CUT = 5.0f;
    const float PI = 3.14159265358979323846f;
    float fc = (dd < CUT) ? 0.5f * (cosf(PI * dd / CUT) + 1.0f) : 0.0f;
    fcutv[e] = fc;
    const float width = CUT / (NRBF - 1);
    const float coeff = -0.5f / (width * width);
#pragma unroll
    for (int k = 0; k < NRBF; ++k) {
        float diff = dd - (float)k * width;
        phifc[e * NRBF + k] = f2b(expf(coeff * diff * diff) * fc);
    }
}

// ---------------- initial q from embedding ----------------
__global__ void embed_kernel(const int* __restrict__ z, const float* __restrict__ emb,
                             float* __restrict__ q, int N) {
    int idx = blockIdx.x * blockDim.x + threadIdx.x;
    if (idx >= N * F) return;
    int n = idx >> 7, f = idx & 127;
    q[idx] = emb[z[n] * F + f];
}

// ---------------- CSR build ----------------
__global__ void count_kernel(const int* __restrict__ ii, int* __restrict__ counts, int E) {
    int e = blockIdx.x * blockDim.x + threadIdx.x;
    if (e < E) atomicAdd(&counts[ii[e]], 1);
}

__global__ void scan_kernel(const int* __restrict__ counts, int* __restrict__ offs, int N) {
    __shared__ int cum[1024];
    int t = threadIdx.x;
    int chunk = (N + 1023) >> 10;
    int b = t * chunk;
    int e = b + chunk; if (e > N) e = N;
    int s = 0;
    for (int a = b; a < e; ++a) s += counts[a];
    cum[t] = s;
    __syncthreads();
    for (int o = 1; o < 1024; o <<= 1) {
        int u = (t >= o) ? cum[t - o] : 0;
        __syncthreads();
        cum[t] += u;
        __syncthreads();
    }
    int run = cum[t] - s;
    for (int a = b; a < e; ++a) { offs[a] = run; run += counts[a]; }
    if (t == 1023) offs[N] = cum[1023];
}

__global__ void fill_kernel(const int* __restrict__ ii, const int* __restrict__ offs,
                            int* __restrict__ cursor, int* __restrict__ elist, int E) {
    int e = blockIdx.x * blockDim.x + threadIdx.x;
    if (e >= E) return;
    int i = ii[e];
    int p = atomicAdd(&cursor[i], 1);
    elist[offs[i] + p] = e;
}

// ---------------- atom_x via MFMA: X = silu(Q@W1+b1)@W2+b2, 32 atoms/block ----------------
__global__ __launch_bounds__(256) void atom_x_mfma(
    const float* __restrict__ q, const bf16* __restrict__ W1T, const float* __restrict__ b1,
    const bf16* __restrict__ W2T, const float* __restrict__ b2, bf16* __restrict__ x, int N) {
    __shared__ __bf16 H[32][136];
    int tid = threadIdx.x;
    int w = tid >> 6, l = tid & 63;
    int lm = l & 15, q4 = l >> 4;
    int i0 = blockIdx.x * 32;
    // GEMM1: wave w covers H cols [32w, 32w+32)
    f32x4 acc[2][2] = {};
    int r0 = min(i0 + lm, N - 1);
    int r1 = min(i0 + 16 + lm, N - 1);
    for (int kt = 0; kt < 4; ++kt) {
        int ko = kt * 32 + q4 * 8;
        bfrag a0 = cvtf(q + (size_t)r0 * F + ko);
        bfrag a1 = cvtf(q + (size_t)r1 * F + ko);
        bfrag b0 = ldb(W1T + (size_t)(w * 32 + lm) * F + ko);
        bfrag b1f = ldb(W1T + (size_t)(w * 32 + 16 + lm) * F + ko);
        acc[0][0] = __builtin_amdgcn_mfma_f32_16x16x32_bf16(a0, b0, acc[0][0], 0, 0, 0);
        acc[1][0] = __builtin_amdgcn_mfma_f32_16x16x32_bf16(a1, b0, acc[1][0], 0, 0, 0);
        acc[0][1] = __builtin_amdgcn_mfma_f32_16x16x32_bf16(a0, b1f, acc[0][1], 0, 0, 0);
        acc[1][1] = __builtin_amdgcn_mfma_f32_16x16x32_bf16(a1, b1f, acc[1][1], 0, 0, 0);
    }
#pragma unroll
    for (int nt = 0; nt < 2; ++nt) {
        int col = w * 32 + nt * 16 + lm;
        float bb = b1[col];
#pragma unroll
        for (int mt = 0; mt < 2; ++mt)
#pragma unroll
            for (int r = 0; r < 4; ++r) {
                float v = acc[mt][nt][r] + bb;
                H[mt * 16 + q4 * 4 + r][col] = (__bf16)(v / (1.0f + expf(-v)));
            }
    }
    __syncthreads();
    // GEMM2: wave w covers X cols [96w, 96w+96)
#pragma unroll
    for (int j = 0; j < 6; ++j) {
        int n0 = w * 96 + j * 16;
        f32x4 c0 = {}, c1 = {};
        const bf16* bp = W2T + (size_t)(n0 + lm) * F;
        for (int kt = 0; kt < 4; ++kt) {
            int ko = kt * 32 + q4 * 8;
            bfrag a0 = ldsb(&H[lm][ko]);
            bfrag a1 = ldsb(&H[16 + lm][ko]);
            bfrag bf = ldb(bp + ko);
            c0 = __builtin_amdgcn_mfma_f32_16x16x32_bf16(a0, bf, c0, 0, 0, 0);
            c1 = __builtin_amdgcn_mfma_f32_16x16x32_bf16(a1, bf, c1, 0, 0, 0);
        }
        int col = n0 + lm;
        float bb = b2[col];
#pragma unroll
        for (int r = 0; r < 4; ++r) {
            int row0 = i0 + q4 * 4 + r;
            int row1 = row0 + 16;
            if (row0 < N) x[(size_t)row0 * F3 + col] = f2b(c0[r] + bb);
            if (row1 < N) x[(size_t)row1 * F3 + col] = f2b(c1[r] + bb);
        }
    }
}

// ---------------- edge gather (one block per destination atom, no atomics) ----------------
__global__ void edge_gather_kernel(float* __restrict__ q, const bf16* __restrict__ mu_in,
                                   const bf16* __restrict__ x, const float* __restrict__ dirv,
                                   const float* __restrict__ fcutv, const bf16* __restrict__ phifc,
                                   const float* __restrict__ fW_f, const float* __restrict__ fb_f,
                                   int t, const int* __restrict__ offs, const int* __restrict__ elist,
                                   const int* __restrict__ jj, bf16* __restrict__ mu_out, int N) {
    int i = blockIdx.x;
    int f = threadIdx.x;
    const float* fWt = fW_f + t * F3;
    const float* fbt = fb_f + t * F3;
    float w0[NRBF], w1[NRBF], w2[NRBF];
#pragma unroll
    for (int k = 0; k < NRBF; ++k) {
        const float* row = fWt + k * (3 * F * NITER);
        w0[k] = row[f];
        w1[k] = row[f + 128];
        w2[k] = row[f + 256];
    }
    float fb0 = fbt[f], fb1 = fbt[f + 128], fb2 = fbt[f + 256];
    int beg = offs[i], end = offs[i + 1];
    float accq = 0.0f, am0 = 0.0f, am1 = 0.0f, am2 = 0.0f;
    for (int l = beg; l < end; ++l) {
        int e = elist[l];
        int j = jj[e];
        float fc = fcutv[e];
        float f0 = fc * fb0, f1 = fc * fb1, f2 = fc * fb2;
#pragma unroll
        for (int k = 0; k < NRBF; ++k) {
            float ph = b2f(phifc[e * NRBF + k]);
            f0 += ph * w0[k];
            f1 += ph * w1[k];
            f2 += ph * w2[k];
        }
        const bf16* xj = x + (size_t)j * F3;
        float dq = f0 * b2f(xj[f]);
        float dR = f1 * b2f(xj[f + 128]);
        float dM = f2 * b2f(xj[f + 256]);
        accq += dq;
        float d0 = dirv[e * 3 + 0], d1 = dirv[e * 3 + 1], d2 = dirv[e * 3 + 2];
        const bf16* muj = mu_in + (size_t)j * F3;
        am0 += dR * d0 + dM * b2f(muj[f]);
        am1 += dR * d1 + dM * b2f(muj[f + 128]);
        am2 += dR * d2 + dM * b2f(muj[f + 256]);
    }
    q[(size_t)i * F + f] += accq;
    mu_out[(size_t)i * F3 + f]       = f2b(b2f(mu_in[(size_t)i * F3 + f]) + am0);
    mu_out[(size_t)i * F3 + 128 + f] = f2b(b2f(mu_in[(size_t)i * F3 + 128 + f]) + am1);
    mu_out[(size_t)i * F3 + 256 + f] = f2b(b2f(mu_in[(size_t)i * F3 + 256 + f]) + am2);
}

// ---------------- mixing via MFMA, 16 atoms/block ----------------
__global__ __launch_bounds__(256) void mix_mfma(
    float* __restrict__ q, bf16* __restrict__ mu,
    const bf16* __restrict__ WmixT, const bf16* __restrict__ W1T, const float* __restrict__ b1,
    const bf16* __restrict__ W2T, const float* __restrict__ b2, int N) {
    __shared__ __bf16 MM[48][264];   // cols 0:128 = V, 128:256 = W
    __shared__ __bf16 CT[16][264];   // ctx = [q | mu_Vn]
    __shared__ __bf16 HM[16][136];
    __shared__ __bf16 Y[16][392];
    int tid = threadIdx.x;
    int w = tid >> 6, l = tid & 63;
    int lm = l & 15, q4 = l >> 4;
    int i0 = blockIdx.x * 16;
    int rowsM = N * 3;
    // GEMM1: MM = MU@Wmix ; wave w: n in [64w, 64w+64), 3 m-tiles
    {
        f32x4 acc[3][4] = {};
        int mr[3];
#pragma unroll
        for (int mt = 0; mt < 3; ++mt) mr[mt] = min(i0 * 3 + mt * 16 + lm, rowsM - 1);
        for (int kt = 0; kt < 4; ++kt) {
            int ko = kt * 32 + q4 * 8;
            bfrag a[3], b[4];
#pragma unroll
            for (int mt = 0; mt < 3; ++mt) a[mt] = ldb(mu + (size_t)mr[mt] * F + ko);
#pragma unroll
            for (int nt = 0; nt < 4; ++nt)
                b[nt] = ldb(WmixT + (size_t)(w * 64 + nt * 16 + lm) * F + ko);
#pragma unroll
            for (int mt = 0; mt < 3; ++mt)
#pragma unroll
                for (int nt = 0; nt < 4; ++nt)
                    acc[mt][nt] = __builtin_amdgcn_mfma_f32_16x16x32_bf16(a[mt], b[nt], acc[mt][nt], 0, 0, 0);
        }
#pragma unroll
        for (int mt = 0; mt < 3; ++mt)
#pragma unroll
            for (int nt = 0; nt < 4; ++nt)
#pragma unroll
                for (int r = 0; r < 4; ++r)
                    MM[mt * 16 + q4 * 4 + r][w * 64 + nt * 16 + lm] = (__bf16)acc[mt][nt][r];
    }
    __syncthreads();
    // ctx = [q | mu_Vn]
    for (int idx = tid; idx < 16 * F; idx += 256) {
        int a = idx >> 7, f = idx & 127;
        int i = min(i0 + a, N - 1);
        float v0 = (float)MM[a * 3 + 0][f];
        float v1 = (float)MM[a * 3 + 1][f];
        float v2 = (float)MM[a * 3 + 2][f];
        CT[a][f] = (__bf16)q[(size_t)i * F + f];
        CT[a][F + f] = (__bf16)sqrtf(v0 * v0 + v1 * v1 + v2 * v2 + 1e-8f);
    }
    __syncthreads();
    // GEMM2: [16,256]@[256,128] ; wave w: n in [32w, 32w+32)
    {
        f32x4 c[2] = {};
        for (int kt = 0; kt < 8; ++kt) {
            int ko = kt * 32 + q4 * 8;
            bfrag a = ldsb(&CT[lm][ko]);
#pragma unroll
            for (int nt = 0; nt < 2; ++nt) {
                bfrag b = ldb(W1T + (size_t)(w * 32 + nt * 16 + lm) * 256 + ko);
                c[nt] = __builtin_amdgcn_mfma_f32_16x16x32_bf16(a, b, c[nt], 0, 0, 0);
            }
        }
#pragma unroll
        for (int nt = 0; nt < 2; ++nt) {
            int col = w * 32 + nt * 16 + lm;
            float bb = b1[col];
#pragma unroll
            for (int r = 0; r < 4; ++r) {
                float v = c[nt][r] + bb;
                HM[q4 * 4 + r][col] = (__bf16)(v / (1.0f + expf(-v)));
            }
        }
    }
    __syncthreads();
    // GEMM3: [16,128]@[128,384] ; wave w: n in [96w, 96w+96)
#pragma unroll
    for (int j = 0; j < 6; ++j) {
        int n0 = w * 96 + j * 16;
        f32x4 c = {};
        const bf16* bp = W2T + (size_t)(n0 + lm) * F;
        for (int kt = 0; kt < 4; ++kt) {
            int ko = kt * 32 + q4 * 8;
            bfrag a = ldsb(&HM[lm][ko]);
            bfrag b = ldb(bp + ko);
            c = __builtin_amdgcn_mfma_f32_16x16x32_bf16(a, b, c, 0, 0, 0);
        }
        int col = n0 + lm;
        float bb = b2[col];
#pragma unroll
        for (int r = 0; r < 4; ++r)
            Y[q4 * 4 + r][col] = (__bf16)(c[r] + bb);
    }
    __syncthreads();
    // epilogue
    for (int idx = tid; idx < 16 * F; idx += 256) {
        int a = idx >> 7, f = idx & 127;
        int i = i0 + a;
        if (i >= N) continue;
        float V0 = (float)MM[a * 3 + 0][f], W0 = (float)MM[a * 3 + 0][F + f];
        float V1 = (float)MM[a * 3 + 1][f], W1v = (float)MM[a * 3 + 1][F + f];
        float V2 = (float)MM[a * 3 + 2][f], W2v = (float)MM[a * 3 + 2][F + f];
        float s = V0 * W0 + V1 * W1v + V2 * W2v;
        float yq = (float)Y[a][f], ym = (float)Y[a][F + f], ys = (float)Y[a][2 * F + f];
        q[(size_t)i * F + f] += yq + ys * s;
        size_t mb = (size_t)i * F3 + f;
        mu[mb]       = f2b(b2f(mu[mb]) + ym * W0);
        mu[mb + 128] = f2b(b2f(mu[mb + 128]) + ym * W1v);
        mu[mb + 256] = f2b(b2f(mu[mb + 256]) + ym * W2v);
    }
}

// ---------------- output: q ‖ mu, dtype per flag ----------------
__global__ void out_kernel(const float* __restrict__ q, const bf16* __restrict__ mu,
                           void* __restrict__ out, int N, const int* __restrict__ flag) {
    int idx = blockIdx.x * blockDim.x + threadIdx.x;
    int nq = N * F;
    int tot = nq + N * F3;
    if (idx >= tot) return;
    float v = (idx < nq) ? q[idx] : b2f(mu[idx - nq]);
    if (*flag) ((float*)out)[idx] = v;
    else       ((bf16*)out)[idx] = f2b(v);
}

extern "C" void kernel_launch(void* const* d_in, const int* in_sizes, int n_in,
                              void* d_out, int out_size, void* d_ws, size_t ws_size,
                              hipStream_t stream) {
    const int* z = (const int*)d_in[0];
    const int* idx_i = (const int*)d_in[2];
    const int* idx_j = (const int*)d_in[3];

    int N = in_sizes[0];
    int E = in_sizes[2];

    char* base = (char*)d_ws;
    size_t off = 0;
    auto alloc = [&](size_t bytes) -> void* {
        void* p = base + off;
        off += (bytes + 255) & ~(size_t)255;
        return p;
    };

    int* flag = (int*)alloc(4);
    float* pos_f = (float*)alloc((size_t)in_sizes[1] * 4);
    float* emb_f = (float*)alloc((size_t)in_sizes[4] * 4);
    float* fW_f = (float*)alloc((size_t)in_sizes[5] * 4);
    float* fb_f = (float*)alloc((size_t)in_sizes[6] * 4);
    float* iW1_f = (float*)alloc((size_t)in_sizes[7] * 4);
    float* ib1_f = (float*)alloc((size_t)in_sizes[8] * 4);
    float* iW2_f = (float*)alloc((size_t)in_sizes[9] * 4);
    float* ib2_f = (float*)alloc((size_t)in_sizes[10] * 4);
    float* mWmix_f = (float*)alloc((size_t)in_sizes[11] * 4);
    float* mW1_f = (float*)alloc((size_t)in_sizes[12] * 4);
    float* mb1_f = (float*)alloc((size_t)in_sizes[13] * 4);
    float* mW2_f = (float*)alloc((size_t)in_sizes[14] * 4);
    float* mb2_f = (float*)alloc((size_t)in_sizes[15] * 4);
    bf16* iW1T = (bf16*)alloc((size_t)NITER * F * F * 2);
    bf16* iW2T = (bf16*)alloc((size_t)NITER * F3 * F * 2);
    bf16* mWmixT = (bf16*)alloc((size_t)NITER * 2 * F * F * 2);
    bf16* mW1T = (bf16*)alloc((size_t)NITER * F * 2 * F * 2);
    bf16* mW2T = (bf16*)alloc((size_t)NITER * F3 * F * 2);
    float* q = (float*)alloc((size_t)N * F * 4);
    bf16* mua = (bf16*)alloc((size_t)N * F3 * 2);
    bf16* mub = (bf16*)alloc((size_t)N * F3 * 2);
    bf16* xbuf = (bf16*)alloc((size_t)N * F3 * 2);
    float* dirv = (float*)alloc((size_t)E * 3 * 4);
    float* fcutv = (float*)alloc((size_t)E * 4);
    bf16* phifc = (bf16*)alloc((size_t)E * NRBF * 2);
    int* counts = (int*)alloc((size_t)N * 4);
    int* offs = (int*)alloc((size_t)(N + 1) * 4);
    int* elist = (int*)alloc((size_t)E * 4);

    hipMemsetAsync(flag, 0, 4, stream);
    detect_kernel<<<64, 256, 0, stream>>>((const unsigned short*)d_in[1], in_sizes[1], flag);

    auto cvt = [&](int idx, float* dst) {
        int n = in_sizes[idx];
        cvt_dual_kernel<<<(n + 255) / 256, 256, 0, stream>>>(d_in[idx], dst, n, flag);
    };
    cvt(1, pos_f);
    cvt(4, emb_f);
    cvt(5, fW_f);  cvt(6, fb_f);
    cvt(7, iW1_f); cvt(8, ib1_f);
    cvt(9, iW2_f); cvt(10, ib2_f);
    cvt(11, mWmix_f);
    cvt(12, mW1_f); cvt(13, mb1_f);
    cvt(14, mW2_f); cvt(15, mb2_f);

    auto tpose = [&](const float* src, bf16* dst, int K, int Nn) {
        int total = NITER * K * Nn;
        transpose_bf16_kernel<<<(total + 255) / 256, 256, 0, stream>>>(src, dst, K, Nn, total);
    };
    tpose(iW1_f, iW1T, F, F);
    tpose(iW2_f, iW2T, F, F3);
    tpose(mWmix_f, mWmixT, F, 2 * F);
    tpose(mW1_f, mW1T, 2 * F, F);
    tpose(mW2_f, mW2T, F, F3);

    geom_kernel<<<(E + 255) / 256, 256, 0, stream>>>(pos_f, idx_i, idx_j, dirv, fcutv, phifc, E);
    embed_kernel<<<(N * F + 255) / 256, 256, 0, stream>>>(z, emb_f, q, N);
    hipMemsetAsync(mua, 0, (size_t)N * F3 * 2, stream);

    hipMemsetAsync(counts, 0, (size_t)N * 4, stream);
    count_kernel<<<(E + 255) / 256, 256, 0, stream>>>(idx_i, counts, E);
    scan_kernel<<<1, 1024, 0, stream>>>(counts, offs, N);
    hipMemsetAsync(counts, 0, (size_t)N * 4, stream);
    fill_kernel<<<(E + 255) / 256, 256, 0, stream>>>(idx_i, offs, counts, elist, E);

    bf16* muin = mua;
    bf16* muout = mub;
    for (int t = 0; t < NITER; ++t) {
        atom_x_mfma<<<(N + 31) / 32, 256, 0, stream>>>(q, iW1T + (size_t)t * F * F, ib1_f + t * F,
                                                       iW2T + (size_t)t * F3 * F, ib2_f + t * F3,
                                                       xbuf, N);
        edge_gather_kernel<<<N, 128, 0, stream>>>(q, muin, xbuf, dirv, fcutv, phifc, fW_f, fb_f,
                                                  t, offs, elist, idx_j, muout, N);
        mix_mfma<<<(N + 15) / 16, 256, 0, stream>>>(q, muout, mWmixT + (size_t)t * 2 * F * F,
                                                    mW1T + (size_t)t * F * 2 * F, mb1_f + t * F,
                                                    mW2T + (size_t)t * F3 * F, mb2_f + t * F3, N);
        bf16* tm = muin; muin = muout; muout = tm;
    }

    int tot = N * (F + F3);
    out_kernel<<<(tot + 255) / 256, 256, 0, stream>>>(q, muin, d_out, N, flag);
}